// Round 1
// baseline (442.635 us; speedup 1.0000x reference)
//
#include <hip/hip_runtime.h>
#include <hip/hip_bf16.h>

#define H2 16
#define HKV 8
#define DHEAD 128
#define HID 1024
#define NQ 2048

typedef unsigned short u16;
typedef __bf16 bf16x8 __attribute__((ext_vector_type(8)));
typedef float f32x4 __attribute__((ext_vector_type(4)));
typedef float f32x16 __attribute__((ext_vector_type(16)));
typedef unsigned int u32x4 __attribute__((ext_vector_type(4)));

__device__ __forceinline__ u16 f2bf(float x) {
    unsigned int u = __float_as_uint(x);
    unsigned int r = (u + 0x7fffu + ((u >> 16) & 1u)) >> 16;
    return (u16)r;
}
__device__ __forceinline__ float bf2f(u16 x) {
    return __uint_as_float(((unsigned int)x) << 16);
}

__device__ __forceinline__ bf16x8 ld_frag(const u16* p) {
    bf16x8 r;
    *reinterpret_cast<uint4*>(&r) = *reinterpret_cast<const uint4*>(p);
    return r;
}

__device__ __forceinline__ void gload_lds16(const u16* g, u16* l) {
    __builtin_amdgcn_global_load_lds((const __attribute__((address_space(1))) void*)g,
                                     (__attribute__((address_space(3))) void*)l, 16, 0, 0);
}

// pack (lo,hi) fp32 -> 2xbf16 (RNE) in one u32
__device__ __forceinline__ unsigned int cvt_pk_bf16(float lo, float hi) {
    unsigned int r;
    asm("v_cvt_pk_bf16_f32 %0, %1, %2" : "=v"(r) : "v"(lo), "v"(hi));
    return r;
}
// a[32:63] <-> b[0:31]
__device__ __forceinline__ void swap32(unsigned int& a, unsigned int& b) {
    asm("v_permlane32_swap_b32 %0, %1" : "+v"(a), "+v"(b));
}

// ---------------- cast x fp32 -> bf16 ----------------
__global__ __launch_bounds__(256) void cast_f32_bf16(const float* __restrict__ in,
                                                     u16* __restrict__ out, int n4) {
    int i = blockIdx.x * 256 + threadIdx.x;
    if (i < n4) {
        float4 v = reinterpret_cast<const float4*>(in)[i];
        ushort4 o;
        o.x = f2bf(v.x); o.y = f2bf(v.y); o.z = f2bf(v.z); o.w = f2bf(v.w);
        reinterpret_cast<ushort4*>(out)[i] = o;
    }
}

// ---------------- all 4 weight transposes in ONE launch ----------------
__global__ __launch_bounds__(256) void transpose_cast_all(const float* __restrict__ Wq,
                                                          const float* __restrict__ Wk,
                                                          const float* __restrict__ Wv,
                                                          const float* __restrict__ Wo,
                                                          u16* __restrict__ Wqkvb,
                                                          u16* __restrict__ Wob) {
    __shared__ u16 t[32][34];
    int bid = blockIdx.x;
    const float* in; u16* out; int K, N, k0, n0;
    if (bid < 2048) {
        in = Wq; out = Wqkvb; K = 1024; N = 2048;
        k0 = (bid & 31) * 32; n0 = (bid >> 5) * 32;
    } else if (bid < 3072) {
        int b = bid - 2048;
        in = Wk; out = Wqkvb + (size_t)2048 * 1024; K = 1024; N = 1024;
        k0 = (b & 31) * 32; n0 = (b >> 5) * 32;
    } else if (bid < 4096) {
        int b = bid - 3072;
        in = Wv; out = Wqkvb + (size_t)3072 * 1024; K = 1024; N = 1024;
        k0 = (b & 31) * 32; n0 = (b >> 5) * 32;
    } else {
        int b = bid - 4096;
        in = Wo; out = Wob; K = 2048; N = 1024;
        k0 = (b & 63) * 32; n0 = (b >> 6) * 32;
    }
    for (int c = threadIdx.x; c < 1024; c += 256) {
        int k = c >> 5, n = c & 31;
        t[k][n] = f2bf(in[(size_t)(k0 + k) * N + n0 + n]);
    }
    __syncthreads();
    for (int c = threadIdx.x; c < 1024; c += 256) {
        int n = c >> 5, k = c & 31;
        out[(size_t)(n0 + n) * K + k0 + k] = t[k][n];
    }
}

// ---------------- GEMM 128x128, BK=64 (two BK=32 slabs) ----------------
template <bool OUT_BF16>
__global__ __launch_bounds__(256) void gemm_bf16_t(const u16* __restrict__ A,
                                                   const u16* __restrict__ Bt,
                                                   void* __restrict__ Cv,
                                                   int M, int N, int K) {
    __shared__ u16 As[2][128 * 32];
    __shared__ u16 Bs[2][128 * 32];
    int tid = threadIdx.x;
    int lane = tid & 63, wave = tid >> 6;
    int quad = lane >> 4, l15 = lane & 15;
    int wr = wave >> 1, wc = wave & 1;
    int m0 = blockIdx.y * 128, n0 = blockIdx.x * 128;

    f32x4 zero = {0.f, 0.f, 0.f, 0.f};
    f32x4 acc[4][4];
    for (int i = 0; i < 4; i++)
        for (int j = 0; j < 4; j++) acc[i][j] = zero;

    int r0 = 16 * wave + (lane >> 2);
    int r1 = r0 + 64;
    int ks0 = (lane & 3) ^ ((r0 >> 1) & 3);
    int ks1 = (lane & 3) ^ ((r1 >> 1) & 3);
    const u16* ga0 = A + (size_t)(m0 + r0) * K + ks0 * 8;
    const u16* ga1 = A + (size_t)(m0 + r1) * K + ks1 * 8;
    const u16* gb0 = Bt + (size_t)(n0 + r0) * K + ks0 * 8;
    const u16* gb1 = Bt + (size_t)(n0 + r1) * K + ks1 * 8;

    int swz = (quad ^ ((l15 >> 1) & 3)) * 8;

    for (int k0 = 0; k0 < K; k0 += 64) {
        __syncthreads();
        #pragma unroll
        for (int s = 0; s < 2; s++) {
            gload_lds16(ga0 + k0 + s * 32, &As[s][wave * 512]);
            gload_lds16(ga1 + k0 + s * 32, &As[s][(wave + 4) * 512]);
            gload_lds16(gb0 + k0 + s * 32, &Bs[s][wave * 512]);
            gload_lds16(gb1 + k0 + s * 32, &Bs[s][(wave + 4) * 512]);
        }
        __syncthreads();
        #pragma unroll
        for (int s = 0; s < 2; s++) {
            bf16x8 a[4], b[4];
            #pragma unroll
            for (int i = 0; i < 4; i++) a[i] = ld_frag(&As[s][(64 * wr + 16 * i + l15) * 32 + swz]);
            #pragma unroll
            for (int j = 0; j < 4; j++) b[j] = ld_frag(&Bs[s][(64 * wc + 16 * j + l15) * 32 + swz]);
            #pragma unroll
            for (int i = 0; i < 4; i++)
                #pragma unroll
                for (int j = 0; j < 4; j++)
                    acc[i][j] = __builtin_amdgcn_mfma_f32_16x16x32_bf16(a[i], b[j], acc[i][j], 0, 0, 0);
        }
    }
    for (int i = 0; i < 4; i++) {
        int rowb = m0 + 64 * wr + 16 * i + quad * 4;
        for (int j = 0; j < 4; j++) {
            int col = n0 + 64 * wc + 16 * j + l15;
            for (int r = 0; r < 4; r++) {
                if (OUT_BF16)
                    ((u16*)Cv)[(size_t)(rowb + r) * N + col] = f2bf(acc[i][j][r]);
                else
                    ((float*)Cv)[(size_t)(rowb + r) * N + col] = acc[i][j][r];
            }
        }
    }
}

// ---------------- GEMM 128x64, BK=64 (Wo) ----------------
__global__ __launch_bounds__(256) void gemm_bf16_n64(const u16* __restrict__ A,
                                                     const u16* __restrict__ Bt,
                                                     float* __restrict__ C,
                                                     int M, int N, int K) {
    __shared__ u16 As[2][128 * 32];
    __shared__ u16 Bs[2][64 * 32];
    int tid = threadIdx.x;
    int lane = tid & 63, wave = tid >> 6;
    int quad = lane >> 4, l15 = lane & 15;
    int m0 = blockIdx.y * 128, n0 = blockIdx.x * 64;

    f32x4 zero = {0.f, 0.f, 0.f, 0.f};
    f32x4 acc[2][4];
    for (int i = 0; i < 2; i++)
        for (int j = 0; j < 4; j++) acc[i][j] = zero;

    int ra0 = 32 * wave + (lane >> 2);
    int ra1 = ra0 + 16;
    int rb  = 16 * wave + (lane >> 2);
    int ksa0 = (lane & 3) ^ ((ra0 >> 1) & 3);
    int ksa1 = (lane & 3) ^ ((ra1 >> 1) & 3);
    int ksb  = (lane & 3) ^ ((rb >> 1) & 3);
    const u16* ga0 = A + (size_t)(m0 + ra0) * K + ksa0 * 8;
    const u16* ga1 = A + (size_t)(m0 + ra1) * K + ksa1 * 8;
    const u16* gb  = Bt + (size_t)(n0 + rb) * K + ksb * 8;

    int swz = (quad ^ ((l15 >> 1) & 3)) * 8;

    for (int k0 = 0; k0 < K; k0 += 64) {
        __syncthreads();
        #pragma unroll
        for (int s = 0; s < 2; s++) {
            gload_lds16(ga0 + k0 + s * 32, &As[s][(2 * wave) * 512]);
            gload_lds16(ga1 + k0 + s * 32, &As[s][(2 * wave + 1) * 512]);
            gload_lds16(gb + k0 + s * 32, &Bs[s][wave * 512]);
        }
        __syncthreads();
        #pragma unroll
        for (int s = 0; s < 2; s++) {
            bf16x8 a[2], b[4];
            #pragma unroll
            for (int i = 0; i < 2; i++) a[i] = ld_frag(&As[s][(32 * wave + 16 * i + l15) * 32 + swz]);
            #pragma unroll
            for (int j = 0; j < 4; j++) b[j] = ld_frag(&Bs[s][(16 * j + l15) * 32 + swz]);
            #pragma unroll
            for (int i = 0; i < 2; i++)
                #pragma unroll
                for (int j = 0; j < 4; j++)
                    acc[i][j] = __builtin_amdgcn_mfma_f32_16x16x32_bf16(a[i], b[j], acc[i][j], 0, 0, 0);
        }
    }
    for (int i = 0; i < 2; i++) {
        int rowb = m0 + 32 * wave + 16 * i + quad * 4;
        for (int j = 0; j < 4; j++) {
            int col = n0 + 16 * j + l15;
            for (int r = 0; r < 4; r++)
                C[(size_t)(rowb + r) * N + col] = acc[i][j][r];
        }
    }
}

// ---------------- fused RMSNorm + RoPE ----------------
__global__ __launch_bounds__(256) void norm_rope_qk(const u16* __restrict__ qkv,
                                                    const float* __restrict__ cosp,
                                                    const float* __restrict__ sinp,
                                                    const float* __restrict__ qnw,
                                                    const float* __restrict__ knw,
                                                    u16* __restrict__ Qb,
                                                    u16* __restrict__ Kb,
                                                    int T, float qscale) {
    int wave = threadIdx.x >> 6, lane = threadIdx.x & 63;
    int wid = blockIdx.x * 4 + wave;
    int t = wid / 24, unit = wid % 24;
    if (t >= T) return;
    bool isq = unit < 16;
    int coloff = isq ? unit * 128 : 2048 + (unit - 16) * 128;
    const float* w = isq ? qnw : knw;
    float outscale = isq ? qscale : 1.0f;
    u16* out = isq ? (Qb + ((size_t)unit * T + t) * 128)
                   : (Kb + ((size_t)(unit - 16) * T + t) * 128);
    const u16* r = qkv + (size_t)t * 4096 + coloff;
    float v1 = bf2f(r[lane]), v2 = bf2f(r[lane + 64]);
    float ss = v1 * v1 + v2 * v2;
    for (int off = 1; off < 64; off <<= 1) ss += __shfl_xor(ss, off);
    float inv = rsqrtf(ss * (1.f / 128.f) + 1e-6f);
    float n1 = v1 * inv * w[lane], n2 = v2 * inv * w[lane + 64];
    float c = cosp[(size_t)t * 64 + lane], s = sinp[(size_t)t * 64 + lane];
    float o1 = (n1 * c - n2 * s) * outscale;
    float o2 = (n1 * s + n2 * c) * outscale;
    out[lane] = f2bf(o1);
    out[lane + 64] = f2bf(o2);
}

// ---------------- V transpose ----------------
__global__ __launch_bounds__(256) void v_transpose(const u16* __restrict__ qkv,
                                                   u16* __restrict__ Vbt, int T) {
    __shared__ u16 tt[128][72];
    int h = blockIdx.y, t0 = blockIdx.x * 64;
    for (int c = threadIdx.x; c < 8192; c += 256) {
        int r = c >> 7, d = c & 127;
        tt[d][r] = qkv[(size_t)(t0 + r) * 4096 + 3072 + h * 128 + d];
    }
    __syncthreads();
    for (int c = threadIdx.x; c < 8192; c += 256) {
        int d = c >> 6, r = c & 63;
        Vbt[((size_t)h * 128 + d) * T + t0 + r] = tt[d][r];
    }
}

// ---------------- causal flash attention, 32x32 MFMA, in-register P ----------------
// Wave (qb,sh): owns q rows [qb*32, qb*32+32) of the 64-row q-tile and s-half sh of
// every 64-wide KV tile. Independent online-softmax state per wave; one flash merge
// per pass via LDS (reusing Ks).
//  QK^T: mfma(A=K, B=Q) -> S^T: q = lane&31, s_local = (r&3)+8*(r>>2)+4*hi (r in 0..15)
//  P fragment built in-register: v_cvt_pk_bf16_f32 pairs + v_permlane32_swap_b32
//  PV:  mfma(A=V^T, B=P^T) -> O[d][q]: q = lane&31 -> alpha/lsum are per-lane scalars.
__global__ __launch_bounds__(256) void flash_attn(const u16* __restrict__ Qb,
                                                  const u16* __restrict__ Kb,
                                                  const u16* __restrict__ Vbt,
                                                  u16* __restrict__ attn, int T) {
    __shared__ u16 Ks[2][64 * 128];   // [s][d], 16B granule g stored at g^(s&7)
    __shared__ u16 Vt[2][128 * 64];   // [d][s], 16B granule g stored at g^(d&7)
    __shared__ float Ms[2][2][32];
    __shared__ float Ls[2][2][32];
    int tid = threadIdx.x;
    int lane = tid & 63, wave = tid >> 6;
    int qb = wave >> 1, sh = wave & 1;
    int l31 = lane & 31, hi = lane >> 5;
    int h = blockIdx.y;
    int j = (int)blockIdx.x;   // 0..31
    int kvh = h >> 1;

    const u16* kbase = Kb + (size_t)kvh * T * 128;
    const u16* vbase = Vbt + (size_t)kvh * 128 * T;

    int krow_ = lane >> 4, kseg_ = lane & 15;
    int vrow_ = lane >> 3, vseg_ = lane & 7;

    auto stage = [&](int s0, int b) {
        #pragma unroll
        for (int i = 0; i < 4; i++) {
            int ch = wave * 4 + i;
            int r = ch * 4 + krow_;
            int s = kseg_ ^ (r & 7);
            gload_lds16(kbase + (size_t)(s0 + r) * 128 + s * 8, &Ks[b][ch * 512]);
        }
        #pragma unroll
        for (int i = 0; i < 4; i++) {
            int ch = wave * 4 + i;
            int d = ch * 8 + vrow_;
            int s = vseg_ ^ (d & 7);
            gload_lds16(vbase + (size_t)d * T + s0 + s * 8, &Vt[b][ch * 512]);
        }
    };

    const float L2E = 1.44269504f;
    int rloc = sh * 32 + l31;           // K row this lane reads

    for (int pass = 0; pass < 2; ++pass) {
        int qt = pass == 0 ? (63 - j) : j;
        int q0 = qt * 64;

        // Q fragments: lane holds Q[q0+qb*32+l31][dstep*16 + hi*8 .. +8)
        bf16x8 qf[8];
        {
            const u16* qp = Qb + ((size_t)h * T + q0 + qb * 32 + l31) * 128 + hi * 8;
            #pragma unroll
            for (int ds_ = 0; ds_ < 8; ds_++) qf[ds_] = ld_frag(qp + ds_ * 16);
        }

        float m_i = -3.0e38f, lsum = 0.f;
        f32x16 o[4];
        #pragma unroll
        for (int db = 0; db < 4; db++)
            #pragma unroll
            for (int r = 0; r < 16; r++) o[db][r] = 0.f;

        int ntiles = qt + 1;
        stage(0, 0);
        __syncthreads();  // tile 0 resident

        for (int it = 0; it < ntiles; ++it) {
            int b = it & 1;
            if (it + 1 < ntiles) stage((it + 1) * 64, 1 - b);
            bool diag = (it == qt);
            // on the diagonal tile, wave (qb=0,sh=1) is fully masked: skip entirely
            // (otherwise mnew = -1e30 makes masked P == 1, corrupting lsum/O)
            if (!(diag && qb == 0 && sh == 1)) {
                // ---- QK^T ----
                f32x16 sc;
                #pragma unroll
                for (int r = 0; r < 16; r++) sc[r] = 0.f;
                __builtin_amdgcn_s_setprio(1);
                #pragma unroll
                for (int ds_ = 0; ds_ < 8; ds_++) {
                    bf16x8 kf = ld_frag(&Ks[b][rloc * 128 + (((ds_ * 2 + hi) ^ (l31 & 7)) * 8)]);
                    sc = __builtin_amdgcn_mfma_f32_32x32x16_bf16(kf, qf[ds_], sc, 0, 0, 0);
                }
                __builtin_amdgcn_s_setprio(0);

                if (diag) {
                    int qg = qb * 32 + l31;
                    #pragma unroll
                    for (int r = 0; r < 16; r++) {
                        int sg = sh * 32 + (r & 3) + ((r >> 2) << 3) + (hi << 2);
                        if (sg > qg) sc[r] = -1e30f;
                    }
                }

                // ---- softmax (per-lane q; other 16 s-values live in lane^32) ----
                float mt = fmaxf(fmaxf(fmaxf(sc[0], sc[1]), fmaxf(sc[2], sc[3])),
                                 fmaxf(fmaxf(sc[4], sc[5]), fmaxf(sc[6], sc[7])));
                float mt2 = fmaxf(fmaxf(fmaxf(sc[8], sc[9]), fmaxf(sc[10], sc[11])),
                                  fmaxf(fmaxf(sc[12], sc[13]), fmaxf(sc[14], sc[15])));
                mt = fmaxf(mt, mt2);
                mt = fmaxf(mt, __shfl_xor(mt, 32));
                float mnew = fmaxf(m_i, mt);
                float alpha = __expf(m_i - mnew);
                m_i = mnew;
                float mls = mnew * L2E;
                #pragma unroll
                for (int r = 0; r < 16; r++) sc[r] = exp2f(fmaf(sc[r], L2E, -mls));
                float ts = ((sc[0] + sc[1]) + (sc[2] + sc[3])) + ((sc[4] + sc[5]) + (sc[6] + sc[7]));
                ts += ((sc[8] + sc[9]) + (sc[10] + sc[11])) + ((sc[12] + sc[13]) + (sc[14] + sc[15]));
                ts += __shfl_xor(ts, 32);
                if (__any(alpha != 1.0f)) {   // rescale only when max advanced
                    lsum = fmaf(lsum, alpha, ts);
                    #pragma unroll
                    for (int db = 0; db < 4; db++)
                        #pragma unroll
                        for (int r = 0; r < 16; r++) o[db][r] *= alpha;
                } else {
                    lsum += ts;
                }

                // ---- P -> bf16 B-fragments in-register + PV ----
                // sstep t2: B[k=hi*8+j][q=l31], k == s_local - t2*16.
                // swap(cvtpk(sc[8t+0],sc[8t+1]), cvtpk(sc[8t+4],sc[8t+5])) -> regs 0,2
                // swap(cvtpk(sc[8t+2],sc[8t+3]), cvtpk(sc[8t+6],sc[8t+7])) -> regs 1,3
                __builtin_amdgcn_s_setprio(1);
                #pragma unroll
                for (int t2 = 0; t2 < 2; t2++) {
                    unsigned int a0 = cvt_pk_bf16(sc[8 * t2 + 0], sc[8 * t2 + 1]);
                    unsigned int a1 = cvt_pk_bf16(sc[8 * t2 + 4], sc[8 * t2 + 5]);
                    unsigned int b0 = cvt_pk_bf16(sc[8 * t2 + 2], sc[8 * t2 + 3]);
                    unsigned int b1 = cvt_pk_bf16(sc[8 * t2 + 6], sc[8 * t2 + 7]);
                    swap32(a0, a1);
                    swap32(b0, b1);
                    u32x4 pw = {a0, b0, a1, b1};
                    bf16x8 pb = *reinterpret_cast<bf16x8*>(&pw);
                    int gD = sh * 4 + t2 * 2 + hi;   // s granule in Vt row
                    #pragma unroll
                    for (int db = 0; db < 4; db++) {
                        int d = db * 32 + l31;
                        bf16x8 vf = ld_frag(&Vt[b][d * 64 + ((gD ^ (d & 7)) * 8)]);
                        o[db] = __builtin_amdgcn_mfma_f32_32x32x16_bf16(vf, pb, o[db], 0, 0, 0);
                    }
                }
                __builtin_amdgcn_s_setprio(0);
            }
            __syncthreads();  // drains next-tile gloads + buffer handoff
        }

        // ---- merge the two s-halves (waves sh=0/1 with same qb) ----
        if (lane < 32) { Ms[qb][sh][l31] = m_i; Ls[qb][sh][l31] = lsum; }
        __syncthreads();
        float mo = Ms[qb][1 - sh][l31];
        float lo_ = Ls[qb][1 - sh][l31];
        float M = fmaxf(m_i, mo);
        float w = __expf(m_i - M);
        float* mbuf = reinterpret_cast<float*>(&Ks[0][0]);  // 32KB scratch: [qb][d:128][q:32]
        if (sh == 1) {
            #pragma unroll
            for (int db = 0; db < 4; db++)
                #pragma unroll
                for (int r = 0; r < 16; r++) {
                    int d = db * 32 + (r & 3) + ((r >> 2) << 3) + (hi << 2);
                    mbuf[((size_t)qb * 128 + d) * 32 + l31] = o[db][r] * w;
                }
        }
        __syncthreads();
        if (sh == 0) {
            float w1 = __expf(mo - M);
            float invl = 1.f / (w * lsum + w1 * lo_);
            #pragma unroll
            for (int db = 0; db < 4; db++)
                #pragma unroll
                for (int r = 0; r < 16; r++) {
                    int d = db * 32 + (r & 3) + ((r >> 2) << 3) + (hi << 2);
                    float val = (o[db][r] * w + mbuf[((size_t)qb * 128 + d) * 32 + l31]) * invl;
                    attn[(size_t)(q0 + qb * 32 + l31) * NQ + h * DHEAD + d] = f2bf(val);
                }
        }
        __syncthreads();  // mbuf free before next pass restages Ks[0]
    }
}

extern "C" void kernel_launch(void* const* d_in, const int* in_sizes, int n_in,
                              void* d_out, int out_size, void* d_ws, size_t ws_size,
                              hipStream_t stream) {
    const float* x    = (const float*)d_in[0];
    const float* cosp = (const float*)d_in[1];
    const float* sinp = (const float*)d_in[2];
    const float* Wq   = (const float*)d_in[3];
    const float* Wk   = (const float*)d_in[4];
    const float* Wv   = (const float*)d_in[5];
    const float* Wo   = (const float*)d_in[6];
    const float* qnw  = (const float*)d_in[7];
    const float* knw  = (const float*)d_in[8];
    float* out = (float*)d_out;
    const int T = in_sizes[1] / 64;  // 4096

    char* ws = (char*)d_ws;
    size_t off = 0;
    auto alloc = [&](size_t bytes) {
        char* p = ws + off;
        off += (bytes + 255) & ~(size_t)255;
        return p;
    };
    u16*   xb     = (u16*)alloc((size_t)T * HID * 2);
    u16*   Wqkvb  = (u16*)alloc((size_t)4096 * HID * 2);
    u16*   Wob    = (u16*)alloc((size_t)HID * NQ * 2);
    u16*   qkvb   = (u16*)alloc((size_t)T * 4096 * 2);
    u16*   Qb     = (u16*)alloc((size_t)H2 * T * DHEAD * 2);
    u16*   Kb     = (u16*)alloc((size_t)HKV * T * DHEAD * 2);
    u16*   Vbt    = (u16*)alloc((size_t)HKV * DHEAD * T * 2);
    u16*   attn   = (u16*)alloc((size_t)T * NQ * 2);

    cast_f32_bf16<<<(T * HID / 4 + 255) / 256, 256, 0, stream>>>(x, xb, T * HID / 4);
    transpose_cast_all<<<6144, 256, 0, stream>>>(Wq, Wk, Wv, Wo, Wqkvb, Wob);

    gemm_bf16_t<true><<<dim3(4096 / 128, T / 128), 256, 0, stream>>>(xb, Wqkvb, qkvb, T, 4096, HID);

    const float scale = 0.08838834764831845f;  // 128^-0.5 folded into Q
    norm_rope_qk<<<T * 24 / 4, 256, 0, stream>>>(qkvb, cosp, sinp, qnw, knw, Qb, Kb, T, scale);
    v_transpose<<<dim3(T / 64, HKV), 256, 0, stream>>>(qkvb, Vbt, T);

    flash_attn<<<dim3(32, H2), 256, 0, stream>>>(Qb, Kb, Vbt, attn, T);

    gemm_bf16_n64<<<dim3(HID / 64, T / 128), 256, 0, stream>>>(attn, Wob, out, T, HID, NQ);
}

// Round 2
// 354.340 us; speedup vs baseline: 1.2492x; 1.2492x over previous
//
#include <hip/hip_runtime.h>
#include <hip/hip_bf16.h>

#define H2 16
#define HKV 8
#define DHEAD 128
#define HID 1024
#define NQ 2048

typedef unsigned short u16;
typedef __bf16 bf16x8 __attribute__((ext_vector_type(8)));
typedef float f32x4 __attribute__((ext_vector_type(4)));

__device__ __forceinline__ u16 f2bf(float x) {
    unsigned int u = __float_as_uint(x);
    unsigned int r = (u + 0x7fffu + ((u >> 16) & 1u)) >> 16;
    return (u16)r;
}
__device__ __forceinline__ float bf2f(u16 x) {
    return __uint_as_float(((unsigned int)x) << 16);
}

// pack two fp32 -> (bf16(hi)<<16)|bf16(lo)
__device__ __forceinline__ unsigned int pack_bf16(float hi, float lo) {
    unsigned int a = __float_as_uint(hi) + 0x8000u;
    unsigned int b = __float_as_uint(lo) + 0x8000u;
    return __builtin_amdgcn_perm(a, b, 0x07060302u);
}

__device__ __forceinline__ bf16x8 ld_frag(const u16* p) {
    bf16x8 r;
    *reinterpret_cast<uint4*>(&r) = *reinterpret_cast<const uint4*>(p);
    return r;
}

__device__ __forceinline__ void gload_lds16(const u16* g, u16* l) {
    __builtin_amdgcn_global_load_lds((const __attribute__((address_space(1))) void*)g,
                                     (__attribute__((address_space(3))) void*)l, 16, 0, 0);
}

// ---------------- cast x fp32 -> bf16 ----------------
__global__ __launch_bounds__(256) void cast_f32_bf16(const float* __restrict__ in,
                                                     u16* __restrict__ out, int n4) {
    int i = blockIdx.x * 256 + threadIdx.x;
    if (i < n4) {
        float4 v = reinterpret_cast<const float4*>(in)[i];
        ushort4 o;
        o.x = f2bf(v.x); o.y = f2bf(v.y); o.z = f2bf(v.z); o.w = f2bf(v.w);
        reinterpret_cast<ushort4*>(out)[i] = o;
    }
}

// ---------------- all 4 weight transposes in ONE launch ----------------
__global__ __launch_bounds__(256) void transpose_cast_all(const float* __restrict__ Wq,
                                                          const float* __restrict__ Wk,
                                                          const float* __restrict__ Wv,
                                                          const float* __restrict__ Wo,
                                                          u16* __restrict__ Wqkvb,
                                                          u16* __restrict__ Wob) {
    __shared__ u16 t[32][34];
    int bid = blockIdx.x;
    const float* in; u16* out; int K, N, k0, n0;
    if (bid < 2048) {
        in = Wq; out = Wqkvb; K = 1024; N = 2048;
        k0 = (bid & 31) * 32; n0 = (bid >> 5) * 32;
    } else if (bid < 3072) {
        int b = bid - 2048;
        in = Wk; out = Wqkvb + (size_t)2048 * 1024; K = 1024; N = 1024;
        k0 = (b & 31) * 32; n0 = (b >> 5) * 32;
    } else if (bid < 4096) {
        int b = bid - 3072;
        in = Wv; out = Wqkvb + (size_t)3072 * 1024; K = 1024; N = 1024;
        k0 = (b & 31) * 32; n0 = (b >> 5) * 32;
    } else {
        int b = bid - 4096;
        in = Wo; out = Wob; K = 2048; N = 1024;
        k0 = (b & 63) * 32; n0 = (b >> 6) * 32;
    }
    for (int c = threadIdx.x; c < 1024; c += 256) {
        int k = c >> 5, n = c & 31;
        t[k][n] = f2bf(in[(size_t)(k0 + k) * N + n0 + n]);
    }
    __syncthreads();
    for (int c = threadIdx.x; c < 1024; c += 256) {
        int n = c >> 5, k = c & 31;
        out[(size_t)(n0 + n) * K + k0 + k] = t[k][n];
    }
}

// ---------------- GEMM 128x128, BK=64 (two BK=32 slabs) ----------------
template <bool OUT_BF16>
__global__ __launch_bounds__(256) void gemm_bf16_t(const u16* __restrict__ A,
                                                   const u16* __restrict__ Bt,
                                                   void* __restrict__ Cv,
                                                   int M, int N, int K) {
    __shared__ u16 As[2][128 * 32];
    __shared__ u16 Bs[2][128 * 32];
    int tid = threadIdx.x;
    int lane = tid & 63, wave = tid >> 6;
    int quad = lane >> 4, l15 = lane & 15;
    int wr = wave >> 1, wc = wave & 1;
    int m0 = blockIdx.y * 128, n0 = blockIdx.x * 128;

    f32x4 zero = {0.f, 0.f, 0.f, 0.f};
    f32x4 acc[4][4];
    for (int i = 0; i < 4; i++)
        for (int j = 0; j < 4; j++) acc[i][j] = zero;

    int r0 = 16 * wave + (lane >> 2);
    int r1 = r0 + 64;
    int ks0 = (lane & 3) ^ ((r0 >> 1) & 3);
    int ks1 = (lane & 3) ^ ((r1 >> 1) & 3);
    const u16* ga0 = A + (size_t)(m0 + r0) * K + ks0 * 8;
    const u16* ga1 = A + (size_t)(m0 + r1) * K + ks1 * 8;
    const u16* gb0 = Bt + (size_t)(n0 + r0) * K + ks0 * 8;
    const u16* gb1 = Bt + (size_t)(n0 + r1) * K + ks1 * 8;

    int swz = (quad ^ ((l15 >> 1) & 3)) * 8;

    for (int k0 = 0; k0 < K; k0 += 64) {
        __syncthreads();
        #pragma unroll
        for (int s = 0; s < 2; s++) {
            gload_lds16(ga0 + k0 + s * 32, &As[s][wave * 512]);
            gload_lds16(ga1 + k0 + s * 32, &As[s][(wave + 4) * 512]);
            gload_lds16(gb0 + k0 + s * 32, &Bs[s][wave * 512]);
            gload_lds16(gb1 + k0 + s * 32, &Bs[s][(wave + 4) * 512]);
        }
        __syncthreads();
        #pragma unroll
        for (int s = 0; s < 2; s++) {
            bf16x8 a[4], b[4];
            #pragma unroll
            for (int i = 0; i < 4; i++) a[i] = ld_frag(&As[s][(64 * wr + 16 * i + l15) * 32 + swz]);
            #pragma unroll
            for (int j = 0; j < 4; j++) b[j] = ld_frag(&Bs[s][(64 * wc + 16 * j + l15) * 32 + swz]);
            #pragma unroll
            for (int i = 0; i < 4; i++)
                #pragma unroll
                for (int j = 0; j < 4; j++)
                    acc[i][j] = __builtin_amdgcn_mfma_f32_16x16x32_bf16(a[i], b[j], acc[i][j], 0, 0, 0);
        }
    }
    for (int i = 0; i < 4; i++) {
        int rowb = m0 + 64 * wr + 16 * i + quad * 4;
        for (int j = 0; j < 4; j++) {
            int col = n0 + 64 * wc + 16 * j + l15;
            for (int r = 0; r < 4; r++) {
                if (OUT_BF16)
                    ((u16*)Cv)[(size_t)(rowb + r) * N + col] = f2bf(acc[i][j][r]);
                else
                    ((float*)Cv)[(size_t)(rowb + r) * N + col] = acc[i][j][r];
            }
        }
    }
}

// ---------------- GEMM 128x64, BK=64 (Wo) ----------------
__global__ __launch_bounds__(256) void gemm_bf16_n64(const u16* __restrict__ A,
                                                     const u16* __restrict__ Bt,
                                                     float* __restrict__ C,
                                                     int M, int N, int K) {
    __shared__ u16 As[2][128 * 32];
    __shared__ u16 Bs[2][64 * 32];
    int tid = threadIdx.x;
    int lane = tid & 63, wave = tid >> 6;
    int quad = lane >> 4, l15 = lane & 15;
    int m0 = blockIdx.y * 128, n0 = blockIdx.x * 64;

    f32x4 zero = {0.f, 0.f, 0.f, 0.f};
    f32x4 acc[2][4];
    for (int i = 0; i < 2; i++)
        for (int j = 0; j < 4; j++) acc[i][j] = zero;

    int ra0 = 32 * wave + (lane >> 2);
    int ra1 = ra0 + 16;
    int rb  = 16 * wave + (lane >> 2);
    int ksa0 = (lane & 3) ^ ((ra0 >> 1) & 3);
    int ksa1 = (lane & 3) ^ ((ra1 >> 1) & 3);
    int ksb  = (lane & 3) ^ ((rb >> 1) & 3);
    const u16* ga0 = A + (size_t)(m0 + ra0) * K + ksa0 * 8;
    const u16* ga1 = A + (size_t)(m0 + ra1) * K + ksa1 * 8;
    const u16* gb  = Bt + (size_t)(n0 + rb) * K + ksb * 8;

    int swz = (quad ^ ((l15 >> 1) & 3)) * 8;

    for (int k0 = 0; k0 < K; k0 += 64) {
        __syncthreads();
        #pragma unroll
        for (int s = 0; s < 2; s++) {
            gload_lds16(ga0 + k0 + s * 32, &As[s][(2 * wave) * 512]);
            gload_lds16(ga1 + k0 + s * 32, &As[s][(2 * wave + 1) * 512]);
            gload_lds16(gb + k0 + s * 32, &Bs[s][wave * 512]);
        }
        __syncthreads();
        #pragma unroll
        for (int s = 0; s < 2; s++) {
            bf16x8 a[2], b[4];
            #pragma unroll
            for (int i = 0; i < 2; i++) a[i] = ld_frag(&As[s][(32 * wave + 16 * i + l15) * 32 + swz]);
            #pragma unroll
            for (int j = 0; j < 4; j++) b[j] = ld_frag(&Bs[s][(16 * j + l15) * 32 + swz]);
            #pragma unroll
            for (int i = 0; i < 2; i++)
                #pragma unroll
                for (int j = 0; j < 4; j++)
                    acc[i][j] = __builtin_amdgcn_mfma_f32_16x16x32_bf16(a[i], b[j], acc[i][j], 0, 0, 0);
        }
    }
    for (int i = 0; i < 2; i++) {
        int rowb = m0 + 32 * wave + 16 * i + quad * 4;
        for (int j = 0; j < 4; j++) {
            int col = n0 + 16 * j + l15;
            for (int r = 0; r < 4; r++)
                C[(size_t)(rowb + r) * N + col] = acc[i][j][r];
        }
    }
}

// ---------------- fused RMSNorm + RoPE ----------------
__global__ __launch_bounds__(256) void norm_rope_qk(const u16* __restrict__ qkv,
                                                    const float* __restrict__ cosp,
                                                    const float* __restrict__ sinp,
                                                    const float* __restrict__ qnw,
                                                    const float* __restrict__ knw,
                                                    u16* __restrict__ Qb,
                                                    u16* __restrict__ Kb,
                                                    int T, float qscale) {
    int wave = threadIdx.x >> 6, lane = threadIdx.x & 63;
    int wid = blockIdx.x * 4 + wave;
    int t = wid / 24, unit = wid % 24;
    if (t >= T) return;
    bool isq = unit < 16;
    int coloff = isq ? unit * 128 : 2048 + (unit - 16) * 128;
    const float* w = isq ? qnw : knw;
    float outscale = isq ? qscale : 1.0f;
    u16* out = isq ? (Qb + ((size_t)unit * T + t) * 128)
                   : (Kb + ((size_t)(unit - 16) * T + t) * 128);
    const u16* r = qkv + (size_t)t * 4096 + coloff;
    float v1 = bf2f(r[lane]), v2 = bf2f(r[lane + 64]);
    float ss = v1 * v1 + v2 * v2;
    for (int off = 1; off < 64; off <<= 1) ss += __shfl_xor(ss, off);
    float inv = rsqrtf(ss * (1.f / 128.f) + 1e-6f);
    float n1 = v1 * inv * w[lane], n2 = v2 * inv * w[lane + 64];
    float c = cosp[(size_t)t * 64 + lane], s = sinp[(size_t)t * 64 + lane];
    float o1 = (n1 * c - n2 * s) * outscale;
    float o2 = (n1 * s + n2 * c) * outscale;
    out[lane] = f2bf(o1);
    out[lane + 64] = f2bf(o2);
}

// ---------------- V transpose ----------------
__global__ __launch_bounds__(256) void v_transpose(const u16* __restrict__ qkv,
                                                   u16* __restrict__ Vbt, int T) {
    __shared__ u16 tt[128][72];
    int h = blockIdx.y, t0 = blockIdx.x * 64;
    for (int c = threadIdx.x; c < 8192; c += 256) {
        int r = c >> 7, d = c & 127;
        tt[d][r] = qkv[(size_t)(t0 + r) * 4096 + 3072 + h * 128 + d];
    }
    __syncthreads();
    for (int c = threadIdx.x; c < 8192; c += 256) {
        int d = c >> 6, r = c & 63;
        Vbt[((size_t)h * 128 + d) * T + t0 + r] = tt[d][r];
    }
}

// ---------------- causal MFMA flash attention, R7 inner loop, 8 waves (s-split) ----------------
// Wave (qw, sh): qw = wave&3 owns q-rows [16*qw,16*qw+16) of the 64-row q-tile;
// sh = wave>>2 owns s-half sh of every 64-wide KV tile. Per-wave online softmax on its
// 32-s half (per-iter code identical to R7 but jt<2 / single kk2); one flash merge per
// pass between the sh-pair through LDS (Ms/Ls + Ks-as-scratch). Doubles waves/SIMD
// (2 -> 4) at identical per-CU MFMA/exp/LDS totals -> hides the ~30% stall fraction.
__global__ __launch_bounds__(512, 4) void flash_attn(const u16* __restrict__ Qb,
                                                     const u16* __restrict__ Kb,
                                                     const u16* __restrict__ Vbt,
                                                     u16* __restrict__ attn, int T) {
    __shared__ u16 Ks[2][64 * 128];
    __shared__ u16 Vt[2][128 * 64];
    __shared__ u16 Ps[64 * 64];
    __shared__ float Ms[4][2][16];
    __shared__ float Ls[4][2][16];
    int tid = threadIdx.x;
    int lane = tid & 63, wave = tid >> 6;   // 0..7
    int qw = wave & 3, sh = wave >> 2;
    int quad = lane >> 4, l15 = lane & 15;
    int swb8 = (l15 & 7) * 8;
    int h = blockIdx.y;
    int j = (int)blockIdx.x;   // 0..31
    int kvh = h >> 1;

    const u16* kbase = Kb + (size_t)kvh * T * 128;
    const u16* vbase = Vbt + (size_t)kvh * 128 * T;

    int krow_ = lane >> 4;
    int kseg_ = lane & 15;
    int vrow_ = lane >> 3;
    int vseg_ = lane & 7;

    auto stage = [&](int s0, int b) {
        #pragma unroll
        for (int i = 0; i < 2; i++) {
            int ch = wave * 2 + i;
            int r = ch * 4 + krow_;
            int s = kseg_ ^ (r & 7);
            gload_lds16(kbase + (size_t)(s0 + r) * 128 + s * 8, &Ks[b][ch * 512]);
        }
        #pragma unroll
        for (int i = 0; i < 2; i++) {
            int ch = wave * 2 + i;
            int d = ch * 8 + vrow_;
            int s = vseg_ ^ (d & 7);
            gload_lds16(vbase + (size_t)d * T + s0 + s * 8, &Vt[b][ch * 512]);
        }
    };

    bf16x8 onesf;
    #pragma unroll
    for (int i = 0; i < 8; i++) onesf[i] = (__bf16)1.0f;
    f32x4 zero = {0.f, 0.f, 0.f, 0.f};
    const float L2E = 1.44269504f;

    for (int pass = 0; pass < 2; ++pass) {
        int qt = pass == 0 ? (63 - j) : j;
        int q0 = qt * 64;

        bf16x8 qf[4];
        {
            const u16* qp = Qb + ((size_t)h * T + q0 + 16 * qw + l15) * 128 + quad * 8;
            #pragma unroll
            for (int kk = 0; kk < 4; kk++) qf[kk] = ld_frag(qp + kk * 32);
        }

        float m_i = -3.0e38f;       // per-lane: q-row = 16*qw + l15
        f32x4 lsum = zero;          // C-layout rows: q = 16*qw + quad*4 + r
        f32x4 o[8];
        for (int dt = 0; dt < 8; dt++) o[dt] = zero;

        int ntiles = qt + 1;
        stage(0, 0);
        __syncthreads();  // tile 0 resident

        for (int it = 0; it < ntiles; ++it) {
            int b = it & 1;
            if (it + 1 < ntiles) stage((it + 1) * 64, 1 - b);
            bool diag = (it == qt);
            // diagonal tile: sh=1 waves with q-rows entirely < 32 are fully masked -> skip
            if (!(diag && sh == 1 && qw < 2)) {
                // S^T: A=K (m->s within own half), B=Q. scT[jt][r]: s = sh*32+jt*16+quad*4+r, q = 16*qw+l15
                f32x4 scT[2];
                scT[0] = zero; scT[1] = zero;
                #pragma unroll
                for (int kk = 0; kk < 4; kk++)
                    #pragma unroll
                    for (int jt = 0; jt < 2; jt++) {
                        bf16x8 kfrag = ld_frag(&Ks[b][(sh * 32 + jt * 16 + l15) * 128 + ((kk * 32 + quad * 8) ^ swb8)]);
                        scT[jt] = __builtin_amdgcn_mfma_f32_16x16x32_bf16(kfrag, qf[kk], scT[jt], 0, 0, 0);
                    }

                if (diag) {  // mask s > q
                    int qloc = 16 * qw + l15;
                    #pragma unroll
                    for (int jt = 0; jt < 2; jt++)
                        for (int r = 0; r < 4; r++)
                            if (sh * 32 + jt * 16 + quad * 4 + r > qloc) scT[jt][r] = -1e30f;
                }

                // lane-local max over 8 scores (same q), then 2-step butterfly across quads
                float mt = scT[0][0];
                #pragma unroll
                for (int jt = 0; jt < 2; jt++)
                    for (int r = 0; r < 4; r++) mt = fmaxf(mt, scT[jt][r]);
                mt = fmaxf(mt, __shfl_xor(mt, 16));
                mt = fmaxf(mt, __shfl_xor(mt, 32));
                float mnew = fmaxf(m_i, mt);
                float alpha = __expf(m_i - mnew);
                m_i = mnew;
                float mls = mnew * L2E;

                #pragma unroll
                for (int jt = 0; jt < 2; jt++)
                    for (int r = 0; r < 4; r++)
                        scT[jt][r] = exp2f(fmaf(scT[jt][r], L2E, -mls));

                // P^T -> Ps[q][s]: wave writes its own (16q x 32s) quadrant
                {
                    int prow = 16 * qw + l15;
                    #pragma unroll
                    for (int jt = 0; jt < 2; jt++) {
                        int s8 = sh * 4 + 2 * jt + (quad >> 1);
                        uint2 wv;
                        wv.x = pack_bf16(scT[jt][1], scT[jt][0]);
                        wv.y = pack_bf16(scT[jt][3], scT[jt][2]);
                        *reinterpret_cast<uint2*>(&Ps[prow * 64 + (s8 ^ (l15 & 7)) * 8 + (quad & 1) * 4]) = wv;
                    }
                }

                // alpha-skip: rescale only when some lane's max advanced
                if (__any(alpha != 1.0f)) {
                    float av[4];
                    #pragma unroll
                    for (int r = 0; r < 4; r++) av[r] = __shfl(alpha, quad * 4 + r);
                    #pragma unroll
                    for (int r = 0; r < 4; r++) lsum[r] *= av[r];
                    #pragma unroll
                    for (int dt = 0; dt < 8; dt++)
                        for (int r = 0; r < 4; r++) o[dt][r] *= av[r];
                }

                asm volatile("s_waitcnt lgkmcnt(0)" ::: "memory");  // wave-private Ps quadrant ordering

                bf16x8 pa = ld_frag(&Ps[(16 * qw + l15) * 64 + (((sh * 4 + quad) ^ (l15 & 7)) * 8)]);
                lsum = __builtin_amdgcn_mfma_f32_16x16x32_bf16(pa, onesf, lsum, 0, 0, 0);
                #pragma unroll
                for (int dt = 0; dt < 8; dt++) {
                    bf16x8 vb = ld_frag(&Vt[b][(dt * 16 + l15) * 64 + (((sh * 4 + quad) * 8) ^ swb8)]);
                    o[dt] = __builtin_amdgcn_mfma_f32_16x16x32_bf16(pa, vb, o[dt], 0, 0, 0);
                }
            }
            __syncthreads();  // drains next-tile loads + buffer handoff
        }

        // ---- merge the two s-halves (waves sh=0/1 with same qw) ----
        if (quad == 0) Ms[qw][sh][l15] = m_i;
        if (l15 == 0) {
            #pragma unroll
            for (int r = 0; r < 4; r++) Ls[qw][sh][quad * 4 + r] = lsum[r];
        }
        __syncthreads();
        float M4[4], wS[4];
        #pragma unroll
        for (int r = 0; r < 4; r++) {
            float mS = Ms[qw][sh][quad * 4 + r];
            float mO = Ms[qw][sh ^ 1][quad * 4 + r];
            M4[r] = fmaxf(mS, mO);
            wS[r] = __expf(mS - M4[r]);
        }
        float* scr = reinterpret_cast<float*>(&Ks[0][0]);  // 32KB: [qw][d:128][q':16]
        if (sh == 1) {
            #pragma unroll
            for (int dt = 0; dt < 8; dt++)
                #pragma unroll
                for (int r = 0; r < 4; r++)
                    scr[qw * 2048 + (dt * 16 + l15) * 16 + ((quad * 4 + r) ^ l15)] = o[dt][r] * wS[r];
        }
        __syncthreads();
        if (sh == 0) {
            float inv[4];
            #pragma unroll
            for (int r = 0; r < 4; r++) {
                float mO = Ms[qw][1][quad * 4 + r];
                float wO = __expf(mO - M4[r]);
                float l = lsum[r] * wS[r] + Ls[qw][1][quad * 4 + r] * wO;
                inv[r] = 1.f / l;
            }
            #pragma unroll
            for (int dt = 0; dt < 8; dt++)
                #pragma unroll
                for (int r = 0; r < 4; r++) {
                    float val = (o[dt][r] * wS[r] +
                                 scr[qw * 2048 + (dt * 16 + l15) * 16 + ((quad * 4 + r) ^ l15)]) * inv[r];
                    int row = q0 + 16 * qw + quad * 4 + r;
                    attn[(size_t)row * NQ + h * DHEAD + dt * 16 + l15] = f2bf(val);
                }
        }
        __syncthreads();  // scr/Ms/Ls free before next pass restages Ks[0]
    }
}

extern "C" void kernel_launch(void* const* d_in, const int* in_sizes, int n_in,
                              void* d_out, int out_size, void* d_ws, size_t ws_size,
                              hipStream_t stream) {
    const float* x    = (const float*)d_in[0];
    const float* cosp = (const float*)d_in[1];
    const float* sinp = (const float*)d_in[2];
    const float* Wq   = (const float*)d_in[3];
    const float* Wk   = (const float*)d_in[4];
    const float* Wv   = (const float*)d_in[5];
    const float* Wo   = (const float*)d_in[6];
    const float* qnw  = (const float*)d_in[7];
    const float* knw  = (const float*)d_in[8];
    float* out = (float*)d_out;
    const int T = in_sizes[1] / 64;  // 4096

    char* ws = (char*)d_ws;
    size_t off = 0;
    auto alloc = [&](size_t bytes) {
        char* p = ws + off;
        off += (bytes + 255) & ~(size_t)255;
        return p;
    };
    u16*   xb     = (u16*)alloc((size_t)T * HID * 2);
    u16*   Wqkvb  = (u16*)alloc((size_t)4096 * HID * 2);
    u16*   Wob    = (u16*)alloc((size_t)HID * NQ * 2);
    u16*   qkvb   = (u16*)alloc((size_t)T * 4096 * 2);
    u16*   Qb     = (u16*)alloc((size_t)H2 * T * DHEAD * 2);
    u16*   Kb     = (u16*)alloc((size_t)HKV * T * DHEAD * 2);
    u16*   Vbt    = (u16*)alloc((size_t)HKV * DHEAD * T * 2);
    u16*   attn   = (u16*)alloc((size_t)T * NQ * 2);

    cast_f32_bf16<<<(T * HID / 4 + 255) / 256, 256, 0, stream>>>(x, xb, T * HID / 4);
    transpose_cast_all<<<6144, 256, 0, stream>>>(Wq, Wk, Wv, Wo, Wqkvb, Wob);

    gemm_bf16_t<true><<<dim3(4096 / 128, T / 128), 256, 0, stream>>>(xb, Wqkvb, qkvb, T, 4096, HID);

    const float scale = 0.08838834764831845f;  // 128^-0.5 folded into Q
    norm_rope_qk<<<T * 24 / 4, 256, 0, stream>>>(qkvb, cosp, sinp, qnw, knw, Qb, Kb, T, scale);
    v_transpose<<<dim3(T / 64, HKV), 256, 0, stream>>>(qkvb, Vbt, T);

    flash_attn<<<dim3(32, H2), 512, 0, stream>>>(Qb, Kb, Vbt, attn, T);

    gemm_bf16_n64<<<dim3(HID / 64, T / 128), 256, 0, stream>>>(attn, Wob, out, T, HID, NQ);
}

// Round 3
// 345.288 us; speedup vs baseline: 1.2819x; 1.0262x over previous
//
#include <hip/hip_runtime.h>
#include <hip/hip_bf16.h>

#define H2 16
#define HKV 8
#define DHEAD 128
#define HID 1024
#define NQ 2048

typedef unsigned short u16;
typedef __bf16 bf16x8 __attribute__((ext_vector_type(8)));
typedef float f32x4 __attribute__((ext_vector_type(4)));

__device__ __forceinline__ u16 f2bf(float x) {
    unsigned int u = __float_as_uint(x);
    unsigned int r = (u + 0x7fffu + ((u >> 16) & 1u)) >> 16;
    return (u16)r;
}
__device__ __forceinline__ float bf2f(u16 x) {
    return __uint_as_float(((unsigned int)x) << 16);
}

// pack two fp32 -> (bf16(hi)<<16)|bf16(lo)
__device__ __forceinline__ unsigned int pack_bf16(float hi, float lo) {
    unsigned int a = __float_as_uint(hi) + 0x8000u;
    unsigned int b = __float_as_uint(lo) + 0x8000u;
    return __builtin_amdgcn_perm(a, b, 0x07060302u);
}

__device__ __forceinline__ bf16x8 ld_frag(const u16* p) {
    bf16x8 r;
    *reinterpret_cast<uint4*>(&r) = *reinterpret_cast<const uint4*>(p);
    return r;
}

__device__ __forceinline__ void gload_lds16(const u16* g, u16* l) {
    __builtin_amdgcn_global_load_lds((const __attribute__((address_space(1))) void*)g,
                                     (__attribute__((address_space(3))) void*)l, 16, 0, 0);
}

// ---------------- cast x fp32 -> bf16 ----------------
__global__ __launch_bounds__(256) void cast_f32_bf16(const float* __restrict__ in,
                                                     u16* __restrict__ out, int n4) {
    int i = blockIdx.x * 256 + threadIdx.x;
    if (i < n4) {
        float4 v = reinterpret_cast<const float4*>(in)[i];
        ushort4 o;
        o.x = f2bf(v.x); o.y = f2bf(v.y); o.z = f2bf(v.z); o.w = f2bf(v.w);
        reinterpret_cast<ushort4*>(out)[i] = o;
    }
}

// ---------------- all 4 weight transposes in ONE launch ----------------
__global__ __launch_bounds__(256) void transpose_cast_all(const float* __restrict__ Wq,
                                                          const float* __restrict__ Wk,
                                                          const float* __restrict__ Wv,
                                                          const float* __restrict__ Wo,
                                                          u16* __restrict__ Wqkvb,
                                                          u16* __restrict__ Wob) {
    __shared__ u16 t[32][34];
    int bid = blockIdx.x;
    const float* in; u16* out; int K, N, k0, n0;
    if (bid < 2048) {
        in = Wq; out = Wqkvb; K = 1024; N = 2048;
        k0 = (bid & 31) * 32; n0 = (bid >> 5) * 32;
    } else if (bid < 3072) {
        int b = bid - 2048;
        in = Wk; out = Wqkvb + (size_t)2048 * 1024; K = 1024; N = 1024;
        k0 = (b & 31) * 32; n0 = (b >> 5) * 32;
    } else if (bid < 4096) {
        int b = bid - 3072;
        in = Wv; out = Wqkvb + (size_t)3072 * 1024; K = 1024; N = 1024;
        k0 = (b & 31) * 32; n0 = (b >> 5) * 32;
    } else {
        int b = bid - 4096;
        in = Wo; out = Wob; K = 2048; N = 1024;
        k0 = (b & 63) * 32; n0 = (b >> 6) * 32;
    }
    for (int c = threadIdx.x; c < 1024; c += 256) {
        int k = c >> 5, n = c & 31;
        t[k][n] = f2bf(in[(size_t)(k0 + k) * N + n0 + n]);
    }
    __syncthreads();
    for (int c = threadIdx.x; c < 1024; c += 256) {
        int n = c >> 5, k = c & 31;
        out[(size_t)(n0 + n) * K + k0 + k] = t[k][n];
    }
}

// ---------------- GEMM 128x128, BK=64 (two BK=32 slabs) ----------------
template <bool OUT_BF16>
__global__ __launch_bounds__(256) void gemm_bf16_t(const u16* __restrict__ A,
                                                   const u16* __restrict__ Bt,
                                                   void* __restrict__ Cv,
                                                   int M, int N, int K) {
    __shared__ u16 As[2][128 * 32];
    __shared__ u16 Bs[2][128 * 32];
    int tid = threadIdx.x;
    int lane = tid & 63, wave = tid >> 6;
    int quad = lane >> 4, l15 = lane & 15;
    int wr = wave >> 1, wc = wave & 1;
    int m0 = blockIdx.y * 128, n0 = blockIdx.x * 128;

    f32x4 zero = {0.f, 0.f, 0.f, 0.f};
    f32x4 acc[4][4];
    for (int i = 0; i < 4; i++)
        for (int j = 0; j < 4; j++) acc[i][j] = zero;

    int r0 = 16 * wave + (lane >> 2);
    int r1 = r0 + 64;
    int ks0 = (lane & 3) ^ ((r0 >> 1) & 3);
    int ks1 = (lane & 3) ^ ((r1 >> 1) & 3);
    const u16* ga0 = A + (size_t)(m0 + r0) * K + ks0 * 8;
    const u16* ga1 = A + (size_t)(m0 + r1) * K + ks1 * 8;
    const u16* gb0 = Bt + (size_t)(n0 + r0) * K + ks0 * 8;
    const u16* gb1 = Bt + (size_t)(n0 + r1) * K + ks1 * 8;

    int swz = (quad ^ ((l15 >> 1) & 3)) * 8;

    for (int k0 = 0; k0 < K; k0 += 64) {
        __syncthreads();
        #pragma unroll
        for (int s = 0; s < 2; s++) {
            gload_lds16(ga0 + k0 + s * 32, &As[s][wave * 512]);
            gload_lds16(ga1 + k0 + s * 32, &As[s][(wave + 4) * 512]);
            gload_lds16(gb0 + k0 + s * 32, &Bs[s][wave * 512]);
            gload_lds16(gb1 + k0 + s * 32, &Bs[s][(wave + 4) * 512]);
        }
        __syncthreads();
        #pragma unroll
        for (int s = 0; s < 2; s++) {
            bf16x8 a[4], b[4];
            #pragma unroll
            for (int i = 0; i < 4; i++) a[i] = ld_frag(&As[s][(64 * wr + 16 * i + l15) * 32 + swz]);
            #pragma unroll
            for (int j = 0; j < 4; j++) b[j] = ld_frag(&Bs[s][(64 * wc + 16 * j + l15) * 32 + swz]);
            #pragma unroll
            for (int i = 0; i < 4; i++)
                #pragma unroll
                for (int j = 0; j < 4; j++)
                    acc[i][j] = __builtin_amdgcn_mfma_f32_16x16x32_bf16(a[i], b[j], acc[i][j], 0, 0, 0);
        }
    }
    for (int i = 0; i < 4; i++) {
        int rowb = m0 + 64 * wr + 16 * i + quad * 4;
        for (int j = 0; j < 4; j++) {
            int col = n0 + 64 * wc + 16 * j + l15;
            for (int r = 0; r < 4; r++) {
                if (OUT_BF16)
                    ((u16*)Cv)[(size_t)(rowb + r) * N + col] = f2bf(acc[i][j][r]);
                else
                    ((float*)Cv)[(size_t)(rowb + r) * N + col] = acc[i][j][r];
            }
        }
    }
}

// ---------------- GEMM 128x64, BK=64 (Wo) ----------------
__global__ __launch_bounds__(256) void gemm_bf16_n64(const u16* __restrict__ A,
                                                     const u16* __restrict__ Bt,
                                                     float* __restrict__ C,
                                                     int M, int N, int K) {
    __shared__ u16 As[2][128 * 32];
    __shared__ u16 Bs[2][64 * 32];
    int tid = threadIdx.x;
    int lane = tid & 63, wave = tid >> 6;
    int quad = lane >> 4, l15 = lane & 15;
    int m0 = blockIdx.y * 128, n0 = blockIdx.x * 64;

    f32x4 zero = {0.f, 0.f, 0.f, 0.f};
    f32x4 acc[2][4];
    for (int i = 0; i < 2; i++)
        for (int j = 0; j < 4; j++) acc[i][j] = zero;

    int ra0 = 32 * wave + (lane >> 2);
    int ra1 = ra0 + 16;
    int rb  = 16 * wave + (lane >> 2);
    int ksa0 = (lane & 3) ^ ((ra0 >> 1) & 3);
    int ksa1 = (lane & 3) ^ ((ra1 >> 1) & 3);
    int ksb  = (lane & 3) ^ ((rb >> 1) & 3);
    const u16* ga0 = A + (size_t)(m0 + ra0) * K + ksa0 * 8;
    const u16* ga1 = A + (size_t)(m0 + ra1) * K + ksa1 * 8;
    const u16* gb  = Bt + (size_t)(n0 + rb) * K + ksb * 8;

    int swz = (quad ^ ((l15 >> 1) & 3)) * 8;

    for (int k0 = 0; k0 < K; k0 += 64) {
        __syncthreads();
        #pragma unroll
        for (int s = 0; s < 2; s++) {
            gload_lds16(ga0 + k0 + s * 32, &As[s][(2 * wave) * 512]);
            gload_lds16(ga1 + k0 + s * 32, &As[s][(2 * wave + 1) * 512]);
            gload_lds16(gb + k0 + s * 32, &Bs[s][wave * 512]);
        }
        __syncthreads();
        #pragma unroll
        for (int s = 0; s < 2; s++) {
            bf16x8 a[2], b[4];
            #pragma unroll
            for (int i = 0; i < 2; i++) a[i] = ld_frag(&As[s][(32 * wave + 16 * i + l15) * 32 + swz]);
            #pragma unroll
            for (int j = 0; j < 4; j++) b[j] = ld_frag(&Bs[s][(16 * j + l15) * 32 + swz]);
            #pragma unroll
            for (int i = 0; i < 2; i++)
                #pragma unroll
                for (int j = 0; j < 4; j++)
                    acc[i][j] = __builtin_amdgcn_mfma_f32_16x16x32_bf16(a[i], b[j], acc[i][j], 0, 0, 0);
        }
    }
    for (int i = 0; i < 2; i++) {
        int rowb = m0 + 32 * wave + 16 * i + quad * 4;
        for (int j = 0; j < 4; j++) {
            int col = n0 + 16 * j + l15;
            for (int r = 0; r < 4; r++)
                C[(size_t)(rowb + r) * N + col] = acc[i][j][r];
        }
    }
}

// ---------------- fused RMSNorm + RoPE ----------------
__global__ __launch_bounds__(256) void norm_rope_qk(const u16* __restrict__ qkv,
                                                    const float* __restrict__ cosp,
                                                    const float* __restrict__ sinp,
                                                    const float* __restrict__ qnw,
                                                    const float* __restrict__ knw,
                                                    u16* __restrict__ Qb,
                                                    u16* __restrict__ Kb,
                                                    int T, float qscale) {
    int wave = threadIdx.x >> 6, lane = threadIdx.x & 63;
    int wid = blockIdx.x * 4 + wave;
    int t = wid / 24, unit = wid % 24;
    if (t >= T) return;
    bool isq = unit < 16;
    int coloff = isq ? unit * 128 : 2048 + (unit - 16) * 128;
    const float* w = isq ? qnw : knw;
    float outscale = isq ? qscale : 1.0f;
    u16* out = isq ? (Qb + ((size_t)unit * T + t) * 128)
                   : (Kb + ((size_t)(unit - 16) * T + t) * 128);
    const u16* r = qkv + (size_t)t * 4096 + coloff;
    float v1 = bf2f(r[lane]), v2 = bf2f(r[lane + 64]);
    float ss = v1 * v1 + v2 * v2;
    for (int off = 1; off < 64; off <<= 1) ss += __shfl_xor(ss, off);
    float inv = rsqrtf(ss * (1.f / 128.f) + 1e-6f);
    float n1 = v1 * inv * w[lane], n2 = v2 * inv * w[lane + 64];
    float c = cosp[(size_t)t * 64 + lane], s = sinp[(size_t)t * 64 + lane];
    float o1 = (n1 * c - n2 * s) * outscale;
    float o2 = (n1 * s + n2 * c) * outscale;
    out[lane] = f2bf(o1);
    out[lane + 64] = f2bf(o2);
}

// ---------------- V transpose ----------------
__global__ __launch_bounds__(256) void v_transpose(const u16* __restrict__ qkv,
                                                   u16* __restrict__ Vbt, int T) {
    __shared__ u16 tt[128][72];
    int h = blockIdx.y, t0 = blockIdx.x * 64;
    for (int c = threadIdx.x; c < 8192; c += 256) {
        int r = c >> 7, d = c & 127;
        tt[d][r] = qkv[(size_t)(t0 + r) * 4096 + 3072 + h * 128 + d];
    }
    __syncthreads();
    for (int c = threadIdx.x; c < 8192; c += 256) {
        int d = c >> 6, r = c & 63;
        Vbt[((size_t)h * 128 + d) * T + t0 + r] = tt[d][r];
    }
}

// ---------------- causal MFMA flash attention: 128-q tile, 2x K/V-frag reuse ----------------
// 8 waves = (qw: 4 x 32 q-rows) x (sh: 2 x 32-s halves). Each wave owns TWO 16-row
// q-subtiles -> every K/V fragment read from LDS feeds 2 MFMAs, and each staged 64-s
// K/V tile serves 128 q-rows. LDS instr per unit work: -43% vs R2 (the measured
// per-CU bottleneck; occupancy was shown immaterial R7 vs R2). Inner code = R2's.
__global__ __launch_bounds__(512, 2) void flash_attn(const u16* __restrict__ Qb,
                                                     const u16* __restrict__ Kb,
                                                     const u16* __restrict__ Vbt,
                                                     u16* __restrict__ attn, int T) {
    __shared__ u16 Ks[2][64 * 128];
    __shared__ u16 Vt[2][128 * 64];
    __shared__ u16 Ps[128 * 64];
    __shared__ float Ms[4][2][32];
    __shared__ float Ls[4][2][32];
    int tid = threadIdx.x;
    int lane = tid & 63, wave = tid >> 6;   // 0..7
    int qw = wave & 3, sh = wave >> 2;
    int quad = lane >> 4, l15 = lane & 15;
    int swb8 = (l15 & 7) * 8;
    int h = blockIdx.y;
    int jj = (int)blockIdx.x;   // 0..T/256-1
    int nqt = T >> 7;           // 128-row q-tiles
    int kvh = h >> 1;

    const u16* kbase = Kb + (size_t)kvh * T * 128;
    const u16* vbase = Vbt + (size_t)kvh * 128 * T;

    int krow_ = lane >> 4;
    int kseg_ = lane & 15;
    int vrow_ = lane >> 3;
    int vseg_ = lane & 7;

    auto stage = [&](int s0, int b) {
        #pragma unroll
        for (int i = 0; i < 2; i++) {
            int ch = wave * 2 + i;
            int r = ch * 4 + krow_;
            int s = kseg_ ^ (r & 7);
            gload_lds16(kbase + (size_t)(s0 + r) * 128 + s * 8, &Ks[b][ch * 512]);
        }
        #pragma unroll
        for (int i = 0; i < 2; i++) {
            int ch = wave * 2 + i;
            int d = ch * 8 + vrow_;
            int s = vseg_ ^ (d & 7);
            gload_lds16(vbase + (size_t)d * T + s0 + s * 8, &Vt[b][ch * 512]);
        }
    };

    bf16x8 onesf;
    #pragma unroll
    for (int i = 0; i < 8; i++) onesf[i] = (__bf16)1.0f;
    f32x4 zero = {0.f, 0.f, 0.f, 0.f};
    const float L2E = 1.44269504f;

    for (int pass = 0; pass < 2; ++pass) {
        int qt = pass == 0 ? (nqt - 1 - jj) : jj;
        int q0 = qt * 128;

        // Q fragments for both 16-row subtiles of this wave's 32 q-rows
        bf16x8 qf[2][4];
        #pragma unroll
        for (int qs = 0; qs < 2; qs++) {
            const u16* qp = Qb + ((size_t)h * T + q0 + 32 * qw + 16 * qs + l15) * 128 + quad * 8;
            #pragma unroll
            for (int kk = 0; kk < 4; kk++) qf[qs][kk] = ld_frag(qp + kk * 32);
        }

        float m_i[2] = {-3.0e38f, -3.0e38f};   // per-lane: q = 32qw + 16qs + l15
        f32x4 lsum[2] = {zero, zero};          // C-layout rows: q = 32qw + 16qs + quad*4 + r
        f32x4 o[2][8];
        #pragma unroll
        for (int qs = 0; qs < 2; qs++)
            #pragma unroll
            for (int dt = 0; dt < 8; dt++) o[qs][dt] = zero;

        int ntiles = 2 * qt + 2;
        stage(0, 0);
        __syncthreads();  // tile 0 resident

        for (int it = 0; it < ntiles; ++it) {
            int b = it & 1;
            if (it + 1 < ntiles) stage((it + 1) * 64, 1 - b);
            bool diagzone = (it >= 2 * qt);
            int sbl = (it - 2 * qt) * 64 + 32 * sh;  // s base local to q0 (valid in diagzone)
            bool skip = diagzone && (32 * qw + 31 < sbl);
            if (!skip) {
                // S^T: A=K (own s-half), B=Q (2 subtiles). Each K-frag feeds 2 MFMAs.
                f32x4 scT[2][2];
                scT[0][0] = zero; scT[0][1] = zero; scT[1][0] = zero; scT[1][1] = zero;
                #pragma unroll
                for (int kk = 0; kk < 4; kk++)
                    #pragma unroll
                    for (int jt = 0; jt < 2; jt++) {
                        bf16x8 kfrag = ld_frag(&Ks[b][(32 * sh + 16 * jt + l15) * 128 + ((kk * 32 + quad * 8) ^ swb8)]);
                        scT[0][jt] = __builtin_amdgcn_mfma_f32_16x16x32_bf16(kfrag, qf[0][kk], scT[0][jt], 0, 0, 0);
                        scT[1][jt] = __builtin_amdgcn_mfma_f32_16x16x32_bf16(kfrag, qf[1][kk], scT[1][jt], 0, 0, 0);
                    }

                if (diagzone) {  // mask s > q (local coords, both rel. q0)
                    #pragma unroll
                    for (int qs = 0; qs < 2; qs++) {
                        int qloc = 32 * qw + 16 * qs + l15;
                        #pragma unroll
                        for (int jt = 0; jt < 2; jt++)
                            for (int r = 0; r < 4; r++)
                                if (sbl + 16 * jt + quad * 4 + r > qloc) scT[qs][jt][r] = -1e30f;
                    }
                }

                #pragma unroll
                for (int qs = 0; qs < 2; qs++) {
                    // lane-local max over 8 scores, then butterfly across quads
                    float mt = scT[qs][0][0];
                    #pragma unroll
                    for (int jt = 0; jt < 2; jt++)
                        for (int r = 0; r < 4; r++) mt = fmaxf(mt, scT[qs][jt][r]);
                    mt = fmaxf(mt, __shfl_xor(mt, 16));
                    mt = fmaxf(mt, __shfl_xor(mt, 32));
                    float mnew = fmaxf(m_i[qs], mt);
                    float alpha = __expf(m_i[qs] - mnew);
                    m_i[qs] = mnew;
                    float mls = mnew * L2E;

                    #pragma unroll
                    for (int jt = 0; jt < 2; jt++)
                        for (int r = 0; r < 4; r++)
                            scT[qs][jt][r] = exp2f(fmaf(scT[qs][jt][r], L2E, -mls));

                    // P^T -> Ps[q][s]: own (16q x 32s) quadrant
                    {
                        int prow = 32 * qw + 16 * qs + l15;
                        #pragma unroll
                        for (int jt = 0; jt < 2; jt++) {
                            int s8 = sh * 4 + 2 * jt + (quad >> 1);
                            uint2 wv;
                            wv.x = pack_bf16(scT[qs][jt][1], scT[qs][jt][0]);
                            wv.y = pack_bf16(scT[qs][jt][3], scT[qs][jt][2]);
                            *reinterpret_cast<uint2*>(&Ps[prow * 64 + (s8 ^ (l15 & 7)) * 8 + (quad & 1) * 4]) = wv;
                        }
                    }

                    // alpha-skip rescale
                    if (__any(alpha != 1.0f)) {
                        float av[4];
                        #pragma unroll
                        for (int r = 0; r < 4; r++) av[r] = __shfl(alpha, quad * 4 + r);
                        #pragma unroll
                        for (int r = 0; r < 4; r++) lsum[qs][r] *= av[r];
                        #pragma unroll
                        for (int dt = 0; dt < 8; dt++)
                            for (int r = 0; r < 4; r++) o[qs][dt][r] *= av[r];
                    }
                }

                asm volatile("s_waitcnt lgkmcnt(0)" ::: "memory");  // wave-private Ps ordering

                bf16x8 pa0 = ld_frag(&Ps[(32 * qw + l15) * 64 + (((sh * 4 + quad) ^ (l15 & 7)) * 8)]);
                bf16x8 pa1 = ld_frag(&Ps[(32 * qw + 16 + l15) * 64 + (((sh * 4 + quad) ^ (l15 & 7)) * 8)]);
                lsum[0] = __builtin_amdgcn_mfma_f32_16x16x32_bf16(pa0, onesf, lsum[0], 0, 0, 0);
                lsum[1] = __builtin_amdgcn_mfma_f32_16x16x32_bf16(pa1, onesf, lsum[1], 0, 0, 0);
                #pragma unroll
                for (int dt = 0; dt < 8; dt++) {
                    bf16x8 vb = ld_frag(&Vt[b][(dt * 16 + l15) * 64 + (((sh * 4 + quad) * 8) ^ swb8)]);
                    o[0][dt] = __builtin_amdgcn_mfma_f32_16x16x32_bf16(pa0, vb, o[0][dt], 0, 0, 0);
                    o[1][dt] = __builtin_amdgcn_mfma_f32_16x16x32_bf16(pa1, vb, o[1][dt], 0, 0, 0);
                }
            }
            __syncthreads();  // drains next-tile loads + buffer handoff
        }

        // ---- merge the two s-halves (waves sh=0/1 with same qw) ----
        if (quad == 0) { Ms[qw][sh][l15] = m_i[0]; Ms[qw][sh][16 + l15] = m_i[1]; }
        if (l15 == 0) {
            #pragma unroll
            for (int qs = 0; qs < 2; qs++)
                for (int r = 0; r < 4; r++) Ls[qw][sh][16 * qs + quad * 4 + r] = lsum[qs][r];
        }
        __syncthreads();
        float M4[2][4], wS[2][4];
        #pragma unroll
        for (int qs = 0; qs < 2; qs++)
            for (int r = 0; r < 4; r++) {
                int qidx = 16 * qs + quad * 4 + r;
                float mS = Ms[qw][sh][qidx];
                float mO = Ms[qw][sh ^ 1][qidx];
                M4[qs][r] = fmaxf(mS, mO);
                wS[qs][r] = __expf(mS - M4[qs][r]);
            }
        // scratch: 16KB per qw; qw 0,1 -> Ks (8192 floats), qw 2,3 -> Vt
        float* scr = (qw < 2) ? reinterpret_cast<float*>(&Ks[0][0]) + qw * 4096
                              : reinterpret_cast<float*>(&Vt[0][0]) + (qw - 2) * 4096;
        if (sh == 1) {
            #pragma unroll
            for (int dt = 0; dt < 8; dt++) {
                int d = dt * 16 + l15;
                #pragma unroll
                for (int qs = 0; qs < 2; qs++)
                    for (int r = 0; r < 4; r++) {
                        int qp_ = 16 * qs + quad * 4 + r;
                        scr[d * 32 + (qp_ ^ (d & 31))] = o[qs][dt][r] * wS[qs][r];
                    }
            }
        }
        __syncthreads();
        if (sh == 0) {
            float inv[2][4];
            #pragma unroll
            for (int qs = 0; qs < 2; qs++)
                for (int r = 0; r < 4; r++) {
                    int qidx = 16 * qs + quad * 4 + r;
                    float mO = Ms[qw][1][qidx];
                    float wO = __expf(mO - M4[qs][r]);
                    float l = lsum[qs][r] * wS[qs][r] + Ls[qw][1][qidx] * wO;
                    inv[qs][r] = 1.f / l;
                }
            #pragma unroll
            for (int dt = 0; dt < 8; dt++) {
                int d = dt * 16 + l15;
                #pragma unroll
                for (int qs = 0; qs < 2; qs++)
                    for (int r = 0; r < 4; r++) {
                        int qp_ = 16 * qs + quad * 4 + r;
                        float val = (o[qs][dt][r] * wS[qs][r] + scr[d * 32 + (qp_ ^ (d & 31))]) * inv[qs][r];
                        int row = q0 + 32 * qw + qp_;
                        attn[(size_t)row * NQ + h * DHEAD + d] = f2bf(val);
                    }
            }
        }
        __syncthreads();  // scratch free before next pass restages Ks[0]/Vt[0]
    }
}

extern "C" void kernel_launch(void* const* d_in, const int* in_sizes, int n_in,
                              void* d_out, int out_size, void* d_ws, size_t ws_size,
                              hipStream_t stream) {
    const float* x    = (const float*)d_in[0];
    const float* cosp = (const float*)d_in[1];
    const float* sinp = (const float*)d_in[2];
    const float* Wq   = (const float*)d_in[3];
    const float* Wk   = (const float*)d_in[4];
    const float* Wv   = (const float*)d_in[5];
    const float* Wo   = (const float*)d_in[6];
    const float* qnw  = (const float*)d_in[7];
    const float* knw  = (const float*)d_in[8];
    float* out = (float*)d_out;
    const int T = in_sizes[1] / 64;  // 4096

    char* ws = (char*)d_ws;
    size_t off = 0;
    auto alloc = [&](size_t bytes) {
        char* p = ws + off;
        off += (bytes + 255) & ~(size_t)255;
        return p;
    };
    u16*   xb     = (u16*)alloc((size_t)T * HID * 2);
    u16*   Wqkvb  = (u16*)alloc((size_t)4096 * HID * 2);
    u16*   Wob    = (u16*)alloc((size_t)HID * NQ * 2);
    u16*   qkvb   = (u16*)alloc((size_t)T * 4096 * 2);
    u16*   Qb     = (u16*)alloc((size_t)H2 * T * DHEAD * 2);
    u16*   Kb     = (u16*)alloc((size_t)HKV * T * DHEAD * 2);
    u16*   Vbt    = (u16*)alloc((size_t)HKV * DHEAD * T * 2);
    u16*   attn   = (u16*)alloc((size_t)T * NQ * 2);

    cast_f32_bf16<<<(T * HID / 4 + 255) / 256, 256, 0, stream>>>(x, xb, T * HID / 4);
    transpose_cast_all<<<6144, 256, 0, stream>>>(Wq, Wk, Wv, Wo, Wqkvb, Wob);

    gemm_bf16_t<true><<<dim3(4096 / 128, T / 128), 256, 0, stream>>>(xb, Wqkvb, qkvb, T, 4096, HID);

    const float scale = 0.08838834764831845f;  // 128^-0.5 folded into Q
    norm_rope_qk<<<T * 24 / 4, 256, 0, stream>>>(qkvb, cosp, sinp, qnw, knw, Qb, Kb, T, scale);
    v_transpose<<<dim3(T / 64, HKV), 256, 0, stream>>>(qkvb, Vbt, T);

    flash_attn<<<dim3(T / 256, H2), 512, 0, stream>>>(Qb, Kb, Vbt, attn, T);

    gemm_bf16_n64<<<dim3(HID / 64, T / 128), 256, 0, stream>>>(attn, Wob, out, T, HID, NQ);
}